// Round 3
// baseline (527.970 us; speedup 1.0000x reference)
//
#include <hip/hip_runtime.h>

#define TT 1024
#define NH 16
#define DD 128
#define WIN 256
#define TQ 4
#define CS 64
#define LPITCH 66
#define EPITCH 320
#define PPITCH 68
#define VTP 1032
#define SCALE 0.08838834764831845f

typedef float f32x4 __attribute__((ext_vector_type(4)));
typedef short s16x8 __attribute__((ext_vector_type(8)));

__device__ __forceinline__ ushort f2bf(float x) {
  union { float f; unsigned u; } v; v.f = x;
  unsigned r = v.u + 0x7FFFu + ((v.u >> 16) & 1u);
  return (ushort)(r >> 16);
}
__device__ __forceinline__ float bf2f(ushort u) {
  union { unsigned u; float f; } v; v.u = ((unsigned)u) << 16; return v.f;
}

// ---------- pre-kernel 1: k fp32 -> bf16 ----------
__global__ __launch_bounds__(256)
void conv_k(const float* __restrict__ k, ushort* __restrict__ kb) {
  long long i = ((long long)blockIdx.x * 256 + threadIdx.x) * 8;
  float4 a = *(const float4*)(k + i);
  float4 c = *(const float4*)(k + i + 4);
  union { ushort u[8]; uint4 v; } pk;
  pk.u[0]=f2bf(a.x); pk.u[1]=f2bf(a.y); pk.u[2]=f2bf(a.z); pk.u[3]=f2bf(a.w);
  pk.u[4]=f2bf(c.x); pk.u[5]=f2bf(c.y); pk.u[6]=f2bf(c.z); pk.u[7]=f2bf(c.w);
  *(uint4*)(kb + i) = pk.v;
}

// ---------- pre-kernel 2: v fp32 [b][s][h][d] -> vT bf16 [b][h][d][s(pitch 1032)] ----------
__global__ __launch_bounds__(256)
void trans_v(const float* __restrict__ v, ushort* __restrict__ vT) {
  int blk = blockIdx.x;
  int st = blk & 31, dt = (blk >> 5) & 3, h = (blk >> 7) & 15, b = blk >> 11;
  __shared__ float tile[32][33];
  int c = threadIdx.x & 31, r4 = threadIdx.x >> 5;
#pragma unroll
  for (int rr = 0; rr < 4; ++rr) {
    int s = st * 32 + r4 + rr * 8;
    tile[r4 + rr * 8][c] = v[((long long)(b * TT + s) * NH + h) * DD + dt * 32 + c];
  }
  __syncthreads();
#pragma unroll
  for (int rr = 0; rr < 4; ++rr) {
    int d = dt * 32 + r4 + rr * 8;
    vT[((long long)(b * NH + h) * DD + d) * VTP + st * 32 + c] = f2bf(tile[c][r4 + rr * 8]);
  }
}

// ---------- main kernel: one block per (b, 4-query tile) ----------
__global__ __launch_bounds__(256, 2)
void attn_main(
    const float* __restrict__ q,
    const float* __restrict__ w_pre,  const float* __restrict__ w_post,
    const float* __restrict__ qw1_pre, const float* __restrict__ qw2_pre,
    const float* __restrict__ kw1_pre, const float* __restrict__ kw2_pre,
    const float* __restrict__ qw1_post, const float* __restrict__ qw2_post,
    const float* __restrict__ kw1_post, const float* __restrict__ kw2_post,
    const float* __restrict__ qdd_pre, const float* __restrict__ kdd_pre,
    const float* __restrict__ qdd_post, const float* __restrict__ kdd_post,
    const ushort* __restrict__ kb, const ushort* __restrict__ vT,
    float* __restrict__ out)
{
  const int tid = threadIdx.x;
  const int raw = blockIdx.x;
  const int jb  = (raw & 7) * 64 + (raw >> 3);   // XCD swizzle: t-adjacent -> same XCD
  const int b = jb >> 8, qt = jb & 255;
  const int t0 = qt * TQ;
  const int s0 = (t0 >= WIN) ? (t0 - WIN + 1) : 0;
  const int L  = t0 + TQ - 1 - s0 + 1;
  const int nch = (L + CS - 1) / CS;

  const int lane = tid & 63, wv = tid >> 6;
  const int qi = wv, sl = lane;
  const int tq = t0 + qi;

  __shared__ float  sLog[NH * 4 * LPITCH];   // QK staging, fp32
  __shared__ ushort sE[NH * 4 * EPITCH];     // unnormalized exp, bf16, whole band
  __shared__ float  sMq[2 * 4 * 16 * 16];    // combined per-q matrices, pre+post
  __shared__ ushort sP[NH * 4 * PPITCH];     // post-proj probs (PV A-operand)

  // ---- build Mq = I + W + qw1*qw2^T + diag(1*0+qdd) for both passes ----
  {
    const long long bt0 = (long long)(b * TT + t0);
#pragma unroll
    for (int ii = 0; ii < 8; ++ii) {
      int idx = tid * 8 + ii;
      int n = idx & 15, m = (idx >> 4) & 15, qq = (idx >> 8) & 3, pp = idx >> 10;
      const float* W   = pp ? w_post   : w_pre;
      const float* QW1 = pp ? qw1_post : qw1_pre;
      const float* QW2 = pp ? qw2_post : qw2_pre;
      const float* QDD = pp ? qdd_post : qdd_pre;
      long long btq = bt0 + qq;
      float val = W[m * 16 + n] + QW1[btq * 32 + m * 2] * QW2[btq * 32 + n * 2]
                + QW1[btq * 32 + m * 2 + 1] * QW2[btq * 32 + n * 2 + 1];
      if (m == n) val += 1.0f + QDD[btq * 16 + n];
      sMq[idx] = val;
    }
  }

  // ---- Q fragments (A operand), pre-scaled by 1/sqrt(D) ----
  s16x8 qa[4][4];
  {
    int qrow = lane & 15; if (qrow > 3) qrow = 3;   // rows 4-15 dup row 3 (discarded)
    int koct = lane >> 4;
#pragma unroll
    for (int hh = 0; hh < 4; ++hh) {
      int h = wv * 4 + hh;
      const float* qp = q + ((long long)(b * TT + t0 + qrow) * NH + h) * DD + koct * 8;
#pragma unroll
      for (int kk = 0; kk < 4; ++kk) {
        float4 a = *(const float4*)(qp + kk * 32);
        float4 c = *(const float4*)(qp + kk * 32 + 4);
        union { ushort u[8]; s16x8 v; } pk;
        pk.u[0]=f2bf(a.x*SCALE); pk.u[1]=f2bf(a.y*SCALE); pk.u[2]=f2bf(a.z*SCALE); pk.u[3]=f2bf(a.w*SCALE);
        pk.u[4]=f2bf(c.x*SCALE); pk.u[5]=f2bf(c.y*SCALE); pk.u[6]=f2bf(c.z*SCALE); pk.u[7]=f2bf(c.w*SCALE);
        qa[hh][kk] = pk.v;
      }
    }
  }

  float zpart[16];
#pragma unroll
  for (int n = 0; n < 16; ++n) zpart[n] = 0.f;

  // ================= PASS 1: QK -> pre-proj -> e = exp(logit) =================
  for (int ch = 0; ch < nch; ++ch) {
    // QK MFMA: wave wv does heads 4wv..4wv+3, 4 s-subtiles of the 64-chunk
#pragma unroll
    for (int hh = 0; hh < 4; ++hh) {
      int h = wv * 4 + hh;
#pragma unroll
      for (int st = 0; st < 4; ++st) {
        int sg2 = s0 + ch * CS + st * 16 + (lane & 15);
        if (sg2 > TT - 1) sg2 = TT - 1;
        const ushort* kp = kb + ((long long)(b * TT + sg2) * NH + h) * DD + (lane >> 4) * 8;
        f32x4 acc = {0.f, 0.f, 0.f, 0.f};
#pragma unroll
        for (int kk = 0; kk < 4; ++kk)
          acc = __builtin_amdgcn_mfma_f32_16x16x32_bf16(qa[hh][kk], *(const s16x8*)(kp + kk * 32), acc, 0, 0, 0);
        if (lane < 16) {
#pragma unroll
          for (int jj = 0; jj < 4; ++jj)
            sLog[(h * 4 + jj) * LPITCH + st * 16 + lane] = acc[jj];
        }
      }
    }
    // per-s dynamic weights (issued before the sync -> overlap the barrier wait)
    int sg = s0 + ch * CS + sl;
    int sgc = (sg > TT - 1) ? TT - 1 : sg;
    long long bts = (long long)(b * TT + sgc);
    float kw1r[32], kw2r[32], kddr[16];
    {
      const float4* p1 = (const float4*)(kw1_pre + bts * 32);
#pragma unroll
      for (int i = 0; i < 8; ++i) ((float4*)kw1r)[i] = p1[i];
      const float4* p2 = (const float4*)(kw2_pre + bts * 32);
#pragma unroll
      for (int i = 0; i < 8; ++i) ((float4*)kw2r)[i] = p2[i];
      const float4* p3 = (const float4*)(kdd_pre + bts * 16);
#pragma unroll
      for (int i = 0; i < 4; ++i) ((float4*)kddr)[i] = p3[i];
    }
    __syncthreads();

    // pre-proj: thread = (q = wave, s-col = lane)
    {
      float inp[16];
#pragma unroll
      for (int m = 0; m < 16; ++m) inp[m] = sLog[(m * 4 + qi) * LPITCH + sl];
      float hk0 = 0.f, hk1 = 0.f;
#pragma unroll
      for (int m = 0; m < 16; ++m) {
        hk0 = fmaf(inp[m], kw1r[2 * m], hk0);
        hk1 = fmaf(inp[m], kw1r[2 * m + 1], hk1);
      }
      const float* MQ = &sMq[qi * 256];
      float ret[16];
#pragma unroll
      for (int n = 0; n < 16; ++n) ret[n] = 0.f;
#pragma unroll
      for (int m = 0; m < 16; ++m) {
        float im = inp[m];
#pragma unroll
        for (int n4 = 0; n4 < 4; ++n4) {
          f32x4 w = *(const f32x4*)&MQ[m * 16 + n4 * 4];
          ret[n4*4+0] = fmaf(im, w[0], ret[n4*4+0]);
          ret[n4*4+1] = fmaf(im, w[1], ret[n4*4+1]);
          ret[n4*4+2] = fmaf(im, w[2], ret[n4*4+2]);
          ret[n4*4+3] = fmaf(im, w[3], ret[n4*4+3]);
        }
      }
      bool valid = (sg <= tq) && (sg > tq - WIN);
#pragma unroll
      for (int n = 0; n < 16; ++n) {
        float val = ret[n] + hk0 * kw2r[2*n] + hk1 * kw2r[2*n+1] + inp[n] * kddr[n];
        float e = valid ? __expf(val) : 0.f;   // no max-sub: logits bounded, shift-invariant
        zpart[n] += e;
        sE[(n * 4 + qi) * EPITCH + ch * CS + sl] = f2bf(e);
      }
    }
    __syncthreads();   // sLog free for next chunk's QK
  }

  // ---- Z reduction (only cross-lane op of the softmax) ----
  float rz[16];
#pragma unroll
  for (int n = 0; n < 16; ++n) {
    float z = zpart[n];
    z += __shfl_xor(z, 1);  z += __shfl_xor(z, 2);  z += __shfl_xor(z, 4);
    z += __shfl_xor(z, 8);  z += __shfl_xor(z, 16); z += __shfl_xor(z, 32);
    rz[n] = 1.0f / z;
  }

  // ================= PASS 2: normalize -> post-proj -> PV =================
  f32x4 pv[4][8];
#pragma unroll
  for (int hh = 0; hh < 4; ++hh)
#pragma unroll
    for (int dt = 0; dt < 8; ++dt) pv[hh][dt] = (f32x4){0.f, 0.f, 0.f, 0.f};

  for (int ch = 0; ch < nch; ++ch) {
    int sg = s0 + ch * CS + sl;
    int sgc = (sg > TT - 1) ? TT - 1 : sg;
    long long bts = (long long)(b * TT + sgc);
    float kw1r[32], kw2r[32], kddr[16];
    {
      const float4* p1 = (const float4*)(kw1_post + bts * 32);
#pragma unroll
      for (int i = 0; i < 8; ++i) ((float4*)kw1r)[i] = p1[i];
      const float4* p2 = (const float4*)(kw2_post + bts * 32);
#pragma unroll
      for (int i = 0; i < 8; ++i) ((float4*)kw2r)[i] = p2[i];
      const float4* p3 = (const float4*)(kdd_post + bts * 16);
#pragma unroll
      for (int i = 0; i < 4; ++i) ((float4*)kddr)[i] = p3[i];
    }
    if (ch) __syncthreads();   // sP consumed by previous PV

    // post-proj on normalized probs (sE is same-thread data: no sync needed)
    {
      float P[16];
#pragma unroll
      for (int m = 0; m < 16; ++m)
        P[m] = bf2f(sE[(m * 4 + qi) * EPITCH + ch * CS + sl]) * rz[m];
      float hk0 = 0.f, hk1 = 0.f;
#pragma unroll
      for (int m = 0; m < 16; ++m) {
        hk0 = fmaf(P[m], kw1r[2 * m], hk0);
        hk1 = fmaf(P[m], kw1r[2 * m + 1], hk1);
      }
      const float* MQ = &sMq[1024 + qi * 256];
      float ret[16];
#pragma unroll
      for (int n = 0; n < 16; ++n) ret[n] = 0.f;
#pragma unroll
      for (int m = 0; m < 16; ++m) {
        float im = P[m];
#pragma unroll
        for (int n4 = 0; n4 < 4; ++n4) {
          f32x4 w = *(const f32x4*)&MQ[m * 16 + n4 * 4];
          ret[n4*4+0] = fmaf(im, w[0], ret[n4*4+0]);
          ret[n4*4+1] = fmaf(im, w[1], ret[n4*4+1]);
          ret[n4*4+2] = fmaf(im, w[2], ret[n4*4+2]);
          ret[n4*4+3] = fmaf(im, w[3], ret[n4*4+3]);
        }
      }
#pragma unroll
      for (int n = 0; n < 16; ++n) {
        float val = ret[n] + hk0 * kw2r[2*n] + hk1 * kw2r[2*n+1] + P[n] * kddr[n];
        sP[(n * 4 + qi) * PPITCH + sl] = f2bf(val);
      }
    }
    __syncthreads();

    // PV MFMA: wave wv does heads 4wv..4wv+3
    int arow = lane & 15; if (arow > 3) arow = 3;
#pragma unroll
    for (int hh = 0; hh < 4; ++hh) {
      int h = wv * 4 + hh;
#pragma unroll
      for (int ks = 0; ks < 2; ++ks) {
        s16x8 pa = *(const s16x8*)&sP[(h * 4 + arow) * PPITCH + ks * 32 + (lane >> 4) * 8];
        int sidx = s0 + ch * CS + ks * 32 + (lane >> 4) * 8;
        if (sidx > 1024) sidx = 1024;   // stay within VTP pitch; P'=0 there
        const ushort* vp = vT + ((long long)(b * NH + h) * DD) * VTP + sidx;
#pragma unroll
        for (int dt = 0; dt < 8; ++dt) {
          int d = dt * 16 + (lane & 15);
          s16x8 vb = *(const s16x8*)(vp + (long long)d * VTP);
          pv[hh][dt] = __builtin_amdgcn_mfma_f32_16x16x32_bf16(pa, vb, pv[hh][dt], 0, 0, 0);
        }
      }
    }
  }

  // ---- epilogue: rows 0-3 live in lanes 0-15 ----
  if (lane < 16) {
#pragma unroll
    for (int hh = 0; hh < 4; ++hh) {
      int h = wv * 4 + hh;
#pragma unroll
      for (int dt = 0; dt < 8; ++dt) {
        int d = dt * 16 + lane;
#pragma unroll
        for (int jj = 0; jj < 4; ++jj)
          out[((long long)(b * TT + t0 + jj) * NH + h) * DD + d] = pv[hh][dt][jj];
      }
    }
  }
}

extern "C" void kernel_launch(void* const* d_in, const int* in_sizes, int n_in,
                              void* d_out, int out_size, void* d_ws, size_t ws_size,
                              hipStream_t stream) {
  const float* q        = (const float*)d_in[0];
  const float* k        = (const float*)d_in[1];
  const float* v        = (const float*)d_in[2];
  const float* w_pre    = (const float*)d_in[3];
  const float* w_post   = (const float*)d_in[4];
  const float* qw1_pre  = (const float*)d_in[5];
  const float* qw2_pre  = (const float*)d_in[6];
  const float* kw1_pre  = (const float*)d_in[7];
  const float* kw2_pre  = (const float*)d_in[8];
  const float* qw1_post = (const float*)d_in[9];
  const float* qw2_post = (const float*)d_in[10];
  const float* kw1_post = (const float*)d_in[11];
  const float* kw2_post = (const float*)d_in[12];
  const float* qdd_pre  = (const float*)d_in[13];
  const float* kdd_pre  = (const float*)d_in[14];
  const float* qdd_post = (const float*)d_in[15];
  const float* kdd_post = (const float*)d_in[16];
  float* out = (float*)d_out;

  // workspace: kb (8,388,608 B) | vT (8,454,144 B)
  ushort* kb = (ushort*)d_ws;
  ushort* vT = (ushort*)((char*)d_ws + 8388608ll);

  conv_k<<<2048, 256, 0, stream>>>(k, kb);
  trans_v<<<4096, 256, 0, stream>>>(v, vT);
  attn_main<<<512, 256, 0, stream>>>(
      q, w_pre, w_post,
      qw1_pre, qw2_pre, kw1_pre, kw2_pre,
      qw1_post, qw2_post, kw1_post, kw2_post,
      qdd_pre, kdd_pre, qdd_post, kdd_post,
      kb, vT, out);
}

// Round 4
// 374.514 us; speedup vs baseline: 1.4097x; 1.4097x over previous
//
#include <hip/hip_runtime.h>

#define TT 1024
#define NH 16
#define DD 128
#define WIN 256
#define QT 16
#define NTT 64          // TT/QT
#define EW 288          // banded width per q-tile (271 rounded to 9*32)
#define VTP 1048        // vT s-pitch (covers s0+287+8)
#define SCALE 0.08838834764831845f

typedef float f32x4 __attribute__((ext_vector_type(4)));
typedef short s16x8 __attribute__((ext_vector_type(8)));

__device__ __forceinline__ ushort f2bf(float x) {
  union { float f; unsigned u; } v; v.f = x;
  unsigned r = v.u + 0x7FFFu + ((v.u >> 16) & 1u);
  return (ushort)(r >> 16);
}
__device__ __forceinline__ float bf2f(ushort u) {
  union { unsigned u; float f; } v; v.u = ((unsigned)u) << 16; return v.f;
}

// ---------- fp32 -> bf16 (optional scale), 8 elems/thread ----------
__global__ __launch_bounds__(256)
void convbf(const float* __restrict__ src, ushort* __restrict__ dst, float scale) {
  long long i = ((long long)blockIdx.x * 256 + threadIdx.x) * 8;
  float4 a = *(const float4*)(src + i);
  float4 c = *(const float4*)(src + i + 4);
  union { ushort u[8]; uint4 v; } pk;
  pk.u[0]=f2bf(a.x*scale); pk.u[1]=f2bf(a.y*scale); pk.u[2]=f2bf(a.z*scale); pk.u[3]=f2bf(a.w*scale);
  pk.u[4]=f2bf(c.x*scale); pk.u[5]=f2bf(c.y*scale); pk.u[6]=f2bf(c.z*scale); pk.u[7]=f2bf(c.w*scale);
  *(uint4*)(dst + i) = pk.v;
}

// ---------- v fp32 [b][s][h][d] -> vT bf16 [b][h][d][s(pitch VTP)] ----------
__global__ __launch_bounds__(256)
void trans_v(const float* __restrict__ v, ushort* __restrict__ vT) {
  int blk = blockIdx.x;
  int st = blk & 31, dt = (blk >> 5) & 3, h = (blk >> 7) & 15, b = blk >> 11;
  __shared__ float tile[32][33];
  int c = threadIdx.x & 31, r4 = threadIdx.x >> 5;
#pragma unroll
  for (int rr = 0; rr < 4; ++rr) {
    int s = st * 32 + r4 + rr * 8;
    tile[r4 + rr * 8][c] = v[((long long)(b * TT + s) * NH + h) * DD + dt * 32 + c];
  }
  __syncthreads();
#pragma unroll
  for (int rr = 0; rr < 4; ++rr) {
    int d = dt * 32 + r4 + rr * 8;
    vT[((long long)(b * NH + h) * DD + d) * VTP + st * 32 + c] = f2bf(tile[c][r4 + rr * 8]);
  }
}

// ---------- K1: QK^T + pre-proj + exp -> E, per (b, q-tile16, s-chunk32) ----------
__global__ __launch_bounds__(256, 3)
void k1_qk(const ushort* __restrict__ qb, const ushort* __restrict__ kb,
           const float* __restrict__ w_pre,
           const float* __restrict__ qw1_pre, const float* __restrict__ qw2_pre,
           const float* __restrict__ qdd_pre,
           const float* __restrict__ kw1_pre, const float* __restrict__ kw2_pre,
           const float* __restrict__ kdd_pre,
           ushort* __restrict__ E)
{
  const int tid = threadIdx.x;
  const int raw = blockIdx.x;                    // 1152 = 8 * 144
  const int idx = (raw & 7) * 144 + (raw >> 3);  // XCD: same q-tile groups co-located
  const int ch  = idx % 9;
  const int btt = idx / 9;
  const int b = btt >> 6, tt = btt & 63;
  const int t0 = tt * QT;
  const int s0 = (t0 >= WIN) ? (t0 - WIN + 1) : 0;
  const int lane = tid & 63, wv = tid >> 6;

  __shared__ float sLog[QT * NH * 33];   // [n*16+q]*33 + scol ; head also used as scratch
  __shared__ float sMq[QT * 256];        // [q][m][n]

  // stage qw1/qw2/qdd tiles into sLog scratch
  const long long bt0 = (long long)b * TT + t0;
  if (tid < 128) {
    ((float4*)sLog)[tid]       = ((const float4*)(qw1_pre + bt0 * 32))[tid];
    ((float4*)sLog)[128 + tid] = ((const float4*)(qw2_pre + bt0 * 32))[tid];
  } else if (tid < 192) {
    ((float4*)sLog)[256 + (tid - 128)] = ((const float4*)(qdd_pre + bt0 * 16))[tid - 128];
  }
  __syncthreads();

  // build Mq = I + W + qw1*qw2^T + diag(qdd) for the 16 q rows
#pragma unroll
  for (int ii = 0; ii < 16; ++ii) {
    int e = ii * 256 + tid;                 // consecutive lanes -> conflict-free
    int n = e & 15, m = (e >> 4) & 15, qq = e >> 8;
    float v = w_pre[m * 16 + n]
            + sLog[qq * 32 + 2 * m]     * sLog[512 + qq * 32 + 2 * n]
            + sLog[qq * 32 + 2 * m + 1] * sLog[512 + qq * 32 + 2 * n + 1];
    if (m == n) v += 1.0f + sLog[1024 + qq * 16 + n];
    sMq[e] = v;
  }
  __syncthreads();   // scratch reads done before MFMA overwrites sLog

  // ---- QK MFMA: wave = 4 heads, 2 s-subtiles ----
  {
    s16x8 qa[4][4];
#pragma unroll
    for (int hh = 0; hh < 4; ++hh) {
      int h = wv * 4 + hh;
      const ushort* qp = qb + ((bt0 + (lane & 15)) * NH + h) * DD + (lane >> 4) * 8;
#pragma unroll
      for (int kk = 0; kk < 4; ++kk) qa[hh][kk] = *(const s16x8*)(qp + kk * 32);
    }
#pragma unroll
    for (int st = 0; st < 2; ++st) {
      int s = s0 + ch * 32 + st * 16 + (lane & 15);
      if (s > TT - 1) s = TT - 1;
#pragma unroll
      for (int hh = 0; hh < 4; ++hh) {
        int h = wv * 4 + hh;
        const ushort* kp = kb + (((long long)(b * TT + s) * NH + h)) * DD + (lane >> 4) * 8;
        f32x4 acc = {0.f, 0.f, 0.f, 0.f};
#pragma unroll
        for (int kk = 0; kk < 4; ++kk)
          acc = __builtin_amdgcn_mfma_f32_16x16x32_bf16(qa[hh][kk], *(const s16x8*)(kp + kk * 32), acc, 0, 0, 0);
        int r0 = (lane >> 4) * 4;
#pragma unroll
        for (int j = 0; j < 4; ++j)
          sLog[(h * 16 + r0 + j) * 33 + st * 16 + (lane & 15)] = acc[j];
      }
    }
  }
  __syncthreads();

  // ---- pre-proj + mask + exp -> E ----
  {
    const int scol = tid & 31, qg = tid >> 5;
    const int s = s0 + ch * 32 + scol;
    const int sc = (s > TT - 1) ? TT - 1 : s;
    const long long bts = (long long)b * TT + sc;
    float kw1r[32], kw2r[32], kddr[16];
    {
      const float4* p1 = (const float4*)(kw1_pre + bts * 32);
#pragma unroll
      for (int i = 0; i < 8; ++i) ((float4*)kw1r)[i] = p1[i];
      const float4* p2 = (const float4*)(kw2_pre + bts * 32);
#pragma unroll
      for (int i = 0; i < 8; ++i) ((float4*)kw2r)[i] = p2[i];
      const float4* p3 = (const float4*)(kdd_pre + bts * 16);
#pragma unroll
      for (int i = 0; i < 4; ++i) ((float4*)kddr)[i] = p3[i];
    }
#pragma unroll
    for (int qj = 0; qj < 2; ++qj) {
      const int q = qg + qj * 8;
      const int t = t0 + q;
      float inp[16];
#pragma unroll
      for (int m = 0; m < 16; ++m) inp[m] = sLog[(m * 16 + q) * 33 + scol];
      float hk0 = 0.f, hk1 = 0.f;
#pragma unroll
      for (int m = 0; m < 16; ++m) {
        hk0 = fmaf(inp[m], kw1r[2 * m], hk0);
        hk1 = fmaf(inp[m], kw1r[2 * m + 1], hk1);
      }
      const float* MQ = &sMq[q * 256];
      float ret[16];
#pragma unroll
      for (int n = 0; n < 16; ++n) ret[n] = 0.f;
#pragma unroll
      for (int m = 0; m < 16; ++m) {
        float im = inp[m];
#pragma unroll
        for (int n4 = 0; n4 < 4; ++n4) {
          f32x4 w = *(const f32x4*)&MQ[m * 16 + n4 * 4];
          ret[n4*4+0] = fmaf(im, w[0], ret[n4*4+0]);
          ret[n4*4+1] = fmaf(im, w[1], ret[n4*4+1]);
          ret[n4*4+2] = fmaf(im, w[2], ret[n4*4+2]);
          ret[n4*4+3] = fmaf(im, w[3], ret[n4*4+3]);
        }
      }
      const bool valid = (s <= t) && (s + WIN > t);
      const int eb = ((b * NTT + tt) * NH * QT + q) * EW + ch * 32 + scol;
#pragma unroll
      for (int n = 0; n < 16; ++n) {
        float val = ret[n] + hk0 * kw2r[2*n] + hk1 * kw2r[2*n+1] + inp[n] * kddr[n];
        float ev = valid ? __expf(val) : 0.f;
        E[eb + n * (QT * EW)] = f2bf(ev);
      }
    }
  }
}

// ---------- K2: Z + normalize + post-proj (in-place on E), per (b, t) ----------
__global__ __launch_bounds__(320, 2)
void k2_sm(const float* __restrict__ w_post,
           const float* __restrict__ qw1_post, const float* __restrict__ qw2_post,
           const float* __restrict__ qdd_post,
           const float* __restrict__ kw1_post, const float* __restrict__ kw2_post,
           const float* __restrict__ kdd_post,
           ushort* __restrict__ E)
{
  const int tid = threadIdx.x;
  const int raw = blockIdx.x;                    // 2048 = 8 * 256
  const int idx = (raw & 7) * 256 + (raw >> 3);
  const int b = idx >> 10, t = idx & 1023;
  const int tt = t >> 4, qr = t & 15;
  const int t0 = tt * QT;
  const int s0 = (t0 >= WIN) ? (t0 - WIN + 1) : 0;
  const int c = tid, lane = tid & 63, wv = tid >> 6;

  __shared__ float sMq[256];
  __shared__ float zp[5][16];
  __shared__ float rzS[16];

  const int ebase = ((b * NTT + tt) * NH * QT + qr) * EW;
  float e[16];
#pragma unroll
  for (int n = 0; n < 16; ++n)
    e[n] = (c < EW) ? bf2f(E[ebase + n * (QT * EW) + c]) : 0.f;

  if (tid < 256) {
    int n = tid & 15, m = tid >> 4;
    long long bt = (long long)b * TT + t;
    float v = w_post[m * 16 + n]
            + qw1_post[bt*32 + 2*m]   * qw2_post[bt*32 + 2*n]
            + qw1_post[bt*32 + 2*m+1] * qw2_post[bt*32 + 2*n+1];
    if (m == n) v += 1.0f + qdd_post[bt*16 + n];
    sMq[tid] = v;   // [m][n]
  }

#pragma unroll
  for (int n = 0; n < 16; ++n) {
    float z = e[n];
    z += __shfl_xor(z, 1);  z += __shfl_xor(z, 2);  z += __shfl_xor(z, 4);
    z += __shfl_xor(z, 8);  z += __shfl_xor(z, 16); z += __shfl_xor(z, 32);
    if (lane == 0) zp[wv][n] = z;
  }
  __syncthreads();
  if (tid < 16) {
    float z = zp[0][tid] + zp[1][tid] + zp[2][tid] + zp[3][tid] + zp[4][tid];
    rzS[tid] = 1.0f / z;
  }
  __syncthreads();

  if (c < EW) {
    float P[16];
#pragma unroll
    for (int m = 0; m < 16; ++m) P[m] = e[m] * rzS[m];
    int s = s0 + c; int sc2 = (s > TT - 1) ? TT - 1 : s;
    long long bts = (long long)b * TT + sc2;
    float kw1r[32], kw2r[32], kddr[16];
    {
      const float4* p1 = (const float4*)(kw1_post + bts * 32);
#pragma unroll
      for (int i = 0; i < 8; ++i) ((float4*)kw1r)[i] = p1[i];
      const float4* p2 = (const float4*)(kw2_post + bts * 32);
#pragma unroll
      for (int i = 0; i < 8; ++i) ((float4*)kw2r)[i] = p2[i];
      const float4* p3 = (const float4*)(kdd_post + bts * 16);
#pragma unroll
      for (int i = 0; i < 4; ++i) ((float4*)kddr)[i] = p3[i];
    }
    float hk0 = 0.f, hk1 = 0.f;
#pragma unroll
    for (int m = 0; m < 16; ++m) {
      hk0 = fmaf(P[m], kw1r[2 * m], hk0);
      hk1 = fmaf(P[m], kw1r[2 * m + 1], hk1);
    }
    float ret[16];
#pragma unroll
    for (int n = 0; n < 16; ++n) ret[n] = 0.f;
#pragma unroll
    for (int m = 0; m < 16; ++m) {
      float im = P[m];
#pragma unroll
      for (int n4 = 0; n4 < 4; ++n4) {
        f32x4 w = *(const f32x4*)&sMq[m * 16 + n4 * 4];
        ret[n4*4+0] = fmaf(im, w[0], ret[n4*4+0]);
        ret[n4*4+1] = fmaf(im, w[1], ret[n4*4+1]);
        ret[n4*4+2] = fmaf(im, w[2], ret[n4*4+2]);
        ret[n4*4+3] = fmaf(im, w[3], ret[n4*4+3]);
      }
    }
#pragma unroll
    for (int n = 0; n < 16; ++n) {
      float val = ret[n] + hk0 * kw2r[2*n] + hk1 * kw2r[2*n+1] + P[n] * kddr[n];
      E[ebase + n * (QT * EW) + c] = f2bf(val);
    }
  }
}

// ---------- K3: PV banded GEMM, per (b, h, q-tile16) ----------
__global__ __launch_bounds__(256, 4)
void k3_pv(const ushort* __restrict__ E, const ushort* __restrict__ vT,
           float* __restrict__ out)
{
  const int tid = threadIdx.x;
  const int raw = blockIdx.x;                    // 2048 = 8 * 256
  const int idx = (raw & 7) * 256 + (raw >> 3);  // same (b,h) groups share vT in L2
  const int b = idx >> 10, h = (idx >> 6) & 15, tt = idx & 63;
  const int t0 = tt * QT;
  const int s0 = (t0 >= WIN) ? (t0 - WIN + 1) : 0;
  const int lane = tid & 63, wv = tid >> 6;

  const ushort* Ap = E + ((b * NTT + tt) * NH + h) * QT * EW + (lane & 15) * EW + (lane >> 4) * 8;
  const ushort* Vp = vT + (long long)(b * NH + h) * DD * VTP + s0 + (lane >> 4) * 8;
  const int d0 = wv * 16 + (lane & 15), d1 = d0 + 64;
  f32x4 acc0 = {0.f,0.f,0.f,0.f}, acc1 = {0.f,0.f,0.f,0.f};
#pragma unroll
  for (int kc = 0; kc < 9; ++kc) {
    s16x8 pa = *(const s16x8*)(Ap + kc * 32);
    s16x8 v0 = *(const s16x8*)(Vp + (long long)d0 * VTP + kc * 32);
    s16x8 v1 = *(const s16x8*)(Vp + (long long)d1 * VTP + kc * 32);
    acc0 = __builtin_amdgcn_mfma_f32_16x16x32_bf16(pa, v0, acc0, 0, 0, 0);
    acc1 = __builtin_amdgcn_mfma_f32_16x16x32_bf16(pa, v1, acc1, 0, 0, 0);
  }
  const int r0 = (lane >> 4) * 4;
#pragma unroll
  for (int j = 0; j < 4; ++j) {
    long long ob = ((long long)(b * TT + t0 + r0 + j) * NH + h) * DD;
    out[ob + d0] = acc0[j];
    out[ob + d1] = acc1[j];
  }
}

extern "C" void kernel_launch(void* const* d_in, const int* in_sizes, int n_in,
                              void* d_out, int out_size, void* d_ws, size_t ws_size,
                              hipStream_t stream) {
  const float* q        = (const float*)d_in[0];
  const float* k        = (const float*)d_in[1];
  const float* v        = (const float*)d_in[2];
  const float* w_pre    = (const float*)d_in[3];
  const float* w_post   = (const float*)d_in[4];
  const float* qw1_pre  = (const float*)d_in[5];
  const float* qw2_pre  = (const float*)d_in[6];
  const float* kw1_pre  = (const float*)d_in[7];
  const float* kw2_pre  = (const float*)d_in[8];
  const float* qw1_post = (const float*)d_in[9];
  const float* qw2_post = (const float*)d_in[10];
  const float* kw1_post = (const float*)d_in[11];
  const float* kw2_post = (const float*)d_in[12];
  const float* qdd_pre  = (const float*)d_in[13];
  const float* kdd_pre  = (const float*)d_in[14];
  const float* qdd_post = (const float*)d_in[15];
  const float* kdd_post = (const float*)d_in[16];
  float* out = (float*)d_out;

  // ws: qb 8,388,608 | kb 8,388,608 | vT 8,585,216 | E 18,874,368  (= 44.2 MB)
  ushort* qb = (ushort*)d_ws;
  ushort* kb = (ushort*)((char*)d_ws + 8388608ll);
  ushort* vT = (ushort*)((char*)d_ws + 16777216ll);
  ushort* E  = (ushort*)((char*)d_ws + 25362432ll);

  convbf<<<2048, 256, 0, stream>>>(q, qb, SCALE);   // fold 1/sqrt(D) into qb
  convbf<<<2048, 256, 0, stream>>>(k, kb, 1.0f);
  trans_v<<<4096, 256, 0, stream>>>(v, vT);
  k1_qk<<<1152, 256, 0, stream>>>(qb, kb, w_pre, qw1_pre, qw2_pre, qdd_pre,
                                  kw1_pre, kw2_pre, kdd_pre, E);
  k2_sm<<<2048, 320, 0, stream>>>(w_post, qw1_post, qw2_post, qdd_post,
                                  kw1_post, kw2_post, kdd_post, E);
  k3_pv<<<2048, 256, 0, stream>>>(E, vT, out);
}

// Round 5
// 174.845 us; speedup vs baseline: 3.0196x; 2.1420x over previous
//
#include <hip/hip_runtime.h>

#define TT 1024
#define NH 16
#define DD 128
#define WIN 256
#define SW 288            // stored band width (9 x 32)
#define SCALE 0.08838834764831845f

typedef float f32x4 __attribute__((ext_vector_type(4)));
typedef short s16x8 __attribute__((ext_vector_type(8)));

__device__ __forceinline__ ushort f2bf(float x) {
  union { float f; unsigned u; } v; v.f = x;
  unsigned r = v.u + 0x7FFFu + ((v.u >> 16) & 1u);
  return (ushort)(r >> 16);
}
__device__ __forceinline__ float bf2f(ushort u) {
  union { unsigned u; float f; } v; v.u = ((unsigned)u) << 16; return v.f;
}

// ---------- prep: fp32 [b][t][h][d] -> bf16 [b][h][doct16][t][8] (opt scale) ----------
__global__ __launch_bounds__(256)
void prep_qk(const float* __restrict__ src, ushort* __restrict__ dst, float scale)
{
  const int tid = threadIdx.x;
  const int bidx = blockIdx.x;                 // 512 = b2*h16*tt16
  const int tt = bidx & 15, h = (bidx >> 4) & 15, b = bidx >> 8;
  const int t0 = tt * 64;
  __shared__ float sQ[64 * 132];
#pragma unroll
  for (int it = 0; it < 8; ++it) {
    int idx = tid + it * 256;                  // 2048 float4
    int r = idx >> 5, cg = idx & 31;
    float4 v = *(const float4*)(src + (((long long)(b * TT + t0 + r)) * NH + h) * DD + cg * 4);
    *(float4*)(&sQ[r * 132 + cg * 4]) = v;
  }
  __syncthreads();
#pragma unroll
  for (int it = 0; it < 4; ++it) {
    int idx = tid + it * 256;                  // 1024 items
    int t = idx & 63, doct = idx >> 6;
    union { ushort u[8]; uint4 v; } pk;
#pragma unroll
    for (int e = 0; e < 8; ++e)
      pk.u[e] = f2bf(sQ[t * 132 + doct * 8 + e] * scale);
    *(uint4*)(dst + ((((long long)(b * NH + h)) * 16 + doct) * TT + t0 + t) * 8) = pk.v;
  }
}

// ---------- prep: v fp32 [b][s][h][d] -> bf16 [b][h][soct128][d][8] ----------
__global__ __launch_bounds__(256)
void prep_v(const float* __restrict__ v, ushort* __restrict__ v8)
{
  const int tid = threadIdx.x;
  const int bidx = blockIdx.x;                 // 512 = b2*h16*st16
  const int st = bidx & 15, h = (bidx >> 4) & 15, b = bidx >> 8;
  const int s0 = st * 64;
  __shared__ float sV[64 * 132];
#pragma unroll
  for (int it = 0; it < 8; ++it) {
    int idx = tid + it * 256;
    int r = idx >> 5, cg = idx & 31;
    float4 x = *(const float4*)(v + (((long long)(b * TT + s0 + r)) * NH + h) * DD + cg * 4);
    *(float4*)(&sV[r * 132 + cg * 4]) = x;
  }
  __syncthreads();
#pragma unroll
  for (int it = 0; it < 4; ++it) {
    int idx = tid + it * 256;                  // 1024 items: (so8 x d128)
    int d = idx & 127, so = idx >> 7;
    union { ushort u[8]; uint4 v; } pk;
#pragma unroll
    for (int e = 0; e < 8; ++e)
      pk.u[e] = f2bf(sV[(so * 8 + e) * 132 + d]);
    *(uint4*)(v8 + ((((long long)(b * NH + h)) * 128 + st * 8 + so) * DD + d) * 8) = pk.v;
  }
}

// ---------- KA: QK^T band GEMM per (b,h,32-t tile) -> S bf16 rows ----------
__global__ __launch_bounds__(256, 4)
void ka_qk(const ushort* __restrict__ qb8, const ushort* __restrict__ kb8,
           ushort* __restrict__ S)
{
  const int tid = threadIdx.x;
  const int raw = blockIdx.x;                  // 1024 = 8*128
  const int job = (raw & 7) * 128 + (raw >> 3);
  const int b = job >> 9, h = (job >> 5) & 15, tt = job & 31;
  const int t0 = tt * 32;
  const int s0 = (t0 >= WIN) ? t0 - WIN : 0;
  const int lane = tid & 63, wv = tid >> 6;

  __shared__ float strip[16 * 300];

  const ushort* qbase = qb8 + ((long long)(b * NH + h)) * 16 * (TT * 8);
  const ushort* kbase = kb8 + ((long long)(b * NH + h)) * 16 * (TT * 8);

  for (int rt = 0; rt < 2; ++rt) {
    const int tlo = t0 + rt * 16;
    s16x8 qa[4];
    {
      const int trow = tlo + (lane & 15);
      const int ko = lane >> 4;
#pragma unroll
      for (int kk = 0; kk < 4; ++kk)
        qa[kk] = *(const s16x8*)(qbase + ((long long)(kk * 4 + ko)) * (TT * 8) + trow * 8);
    }
    int cl0 = tlo - (WIN - 1) - s0; if (cl0 < 0) cl0 = 0;
    const int chi = tlo + 15 - s0;
    const int stb = cl0 >> 4;
    const int nst = (chi >> 4) - stb + 1;
    for (int sti = wv; sti < nst; sti += 4) {
      const int cst = (stb + sti) * 16;
      const int scol = s0 + cst + (lane & 15);
      const int ko = lane >> 4;
      f32x4 acc = {0.f, 0.f, 0.f, 0.f};
#pragma unroll
      for (int kk = 0; kk < 4; ++kk) {
        s16x8 kb = *(const s16x8*)(kbase + ((long long)(kk * 4 + ko)) * (TT * 8) + scol * 8);
        acc = __builtin_amdgcn_mfma_f32_16x16x32_bf16(qa[kk], kb, acc, 0, 0, 0);
      }
      const int r0 = (lane >> 4) * 4;
#pragma unroll
      for (int j = 0; j < 4; ++j)
        strip[(r0 + j) * 300 + cst + (lane & 15)] = acc[j];
    }
    __syncthreads();
    const long long srow0 = (((long long)(b * NH + h)) * TT + tlo) * SW;
#pragma unroll
    for (int it = 0; it < 3; ++it) {
      int idx = tid + it * 256;
      if (idx < 16 * 36) {
        int r = idx / 36, sg = idx % 36;
        union { ushort u[8]; uint4 v; } pk;
#pragma unroll
        for (int e = 0; e < 8; ++e)
          pk.u[e] = f2bf(strip[r * 300 + sg * 8 + e]);
        *(uint4*)(S + srow0 + (long long)r * SW + sg * 8) = pk.v;
      }
    }
    __syncthreads();
  }
}

// ---------- KB: pre-proj + exp + Z + post-proj, in-place on S, per (b, 2 t) ----------
__global__ __launch_bounds__(256, 3)
void kb_proj(const float* __restrict__ w_pre, const float* __restrict__ w_post,
             const float* __restrict__ qw1_pre, const float* __restrict__ qw2_pre,
             const float* __restrict__ qdd_pre,
             const float* __restrict__ kw1_pre, const float* __restrict__ kw2_pre,
             const float* __restrict__ kdd_pre,
             const float* __restrict__ qw1_post, const float* __restrict__ qw2_post,
             const float* __restrict__ qdd_post,
             const float* __restrict__ kw1_post, const float* __restrict__ kw2_post,
             const float* __restrict__ kdd_post,
             ushort* __restrict__ S)
{
  const int tid = threadIdx.x;
  const int raw = blockIdx.x;                  // 1024 = 8*128
  const int job = (raw & 7) * 128 + (raw >> 3);
  const int b = job >> 9, tp = job & 511;
  const int t0 = tp * 2;
  const int tb32 = t0 & ~31;
  const int s0 = (tb32 >= WIN) ? tb32 - WIN : 0;

  __shared__ ushort sS[16 * 2 * SW];
  __shared__ float skw1[16 * 65 * 2];
  __shared__ float skw2[16 * 65 * 2];
  __shared__ float skdd[16 * 66];
  __shared__ float sMq[2 * 2 * 256];
  __shared__ float srz[32];

  // load S rows (16h x 2t), coalesced
#pragma unroll
  for (int it = 0; it < 5; ++it) {
    int idx = tid + it * 256;
    if (idx < 32 * 36) {
      int r = idx / 36, sg = idx % 36;
      int hh = r >> 1, tjj = r & 1;
      uint4 v = *(const uint4*)(S + ((((long long)(b * NH + hh)) * TT) + t0 + tjj) * SW + sg * 8);
      *(uint4*)(&sS[(hh * 2 + tjj) * SW + sg * 8]) = v;
    }
  }
  // build Mq = I + W + qw1*qw2^T + diag(qdd), both passes, both t
#pragma unroll
  for (int ii = 0; ii < 4; ++ii) {
    int e = tid * 4 + ii;
    int n = e & 15, m = (e >> 4) & 15, tq = (e >> 8) & 1, pp = e >> 9;
    const float* W   = pp ? w_post   : w_pre;
    const float* QW1 = pp ? qw1_post : qw1_pre;
    const float* QW2 = pp ? qw2_post : qw2_pre;
    const float* QDD = pp ? qdd_post : qdd_pre;
    long long btq = (long long)b * TT + t0 + tq;
    float val = W[m * 16 + n]
              + QW1[btq * 32 + 2 * m] * QW2[btq * 32 + 2 * n]
              + QW1[btq * 32 + 2 * m + 1] * QW2[btq * 32 + 2 * n + 1];
    if (m == n) val += 1.0f + QDD[btq * 16 + n];
    sMq[e] = val;
  }
  __syncthreads();

  const int nh = tid >> 7, tj = (tid >> 6) & 1, c = tid & 63;
  const int t = t0 + tj;
  const int n0 = nh * 8;
  float zpart[8];
#pragma unroll
  for (int n = 0; n < 8; ++n) zpart[n] = 0.f;

#define STAGE_KW(KW1, KW2, KDD)                                               \
  {                                                                            \
    _Pragma("unroll")                                                          \
    for (int it = 0; it < 2; ++it) {                                           \
      int idx = tid + it * 256;                                                \
      int s = idx >> 3, f4 = idx & 7;                                          \
      int sg = s0 + ch * 64 + s; if (sg > TT - 1) sg = TT - 1;                 \
      float4 a = *(const float4*)((KW1) + ((long long)b * TT + sg) * 32 + f4 * 4); \
      *(float2*)(&skw1[(2 * f4) * 130 + s * 2])     = make_float2(a.x, a.y);   \
      *(float2*)(&skw1[(2 * f4 + 1) * 130 + s * 2]) = make_float2(a.z, a.w);   \
      float4 w2 = *(const float4*)((KW2) + ((long long)b * TT + sg) * 32 + f4 * 4); \
      *(float2*)(&skw2[(2 * f4) * 130 + s * 2])     = make_float2(w2.x, w2.y); \
      *(float2*)(&skw2[(2 * f4 + 1) * 130 + s * 2]) = make_float2(w2.z, w2.w); \
    }                                                                          \
    {                                                                          \
      int s = tid >> 2, f4 = tid & 3;                                          \
      int sg = s0 + ch * 64 + s; if (sg > TT - 1) sg = TT - 1;                 \
      float4 a = *(const float4*)((KDD) + ((long long)b * TT + sg) * 16 + f4 * 4); \
      skdd[(4 * f4 + 0) * 66 + s] = a.x;                                       \
      skdd[(4 * f4 + 1) * 66 + s] = a.y;                                       \
      skdd[(4 * f4 + 2) * 66 + s] = a.z;                                       \
      skdd[(4 * f4 + 3) * 66 + s] = a.w;                                       \
    }                                                                          \
  }

  // ================= PASS 1 =================
  for (int ch = 0; ch < 5; ++ch) {
    STAGE_KW(kw1_pre, kw2_pre, kdd_pre);
    const int cc = ch * 64 + c;
    float inp[16];
    if (cc < SW) {
#pragma unroll
      for (int m = 0; m < 16; ++m) inp[m] = bf2f(sS[(m * 2 + tj) * SW + cc]);
    }
    __syncthreads();
    if (cc < SW) {
      float hk0 = 0.f, hk1 = 0.f;
      float ret[8] = {0.f,0.f,0.f,0.f,0.f,0.f,0.f,0.f};
#pragma unroll
      for (int m = 0; m < 16; ++m) {
        float2 k1 = *(const float2*)(&skw1[m * 130 + c * 2]);
        hk0 = fmaf(inp[m], k1.x, hk0);
        hk1 = fmaf(inp[m], k1.y, hk1);
        const float* MQ = &sMq[tj * 256 + m * 16 + n0];
        f32x4 w0 = *(const f32x4*)(MQ);
        f32x4 w1 = *(const f32x4*)(MQ + 4);
        ret[0] = fmaf(inp[m], w0[0], ret[0]); ret[1] = fmaf(inp[m], w0[1], ret[1]);
        ret[2] = fmaf(inp[m], w0[2], ret[2]); ret[3] = fmaf(inp[m], w0[3], ret[3]);
        ret[4] = fmaf(inp[m], w1[0], ret[4]); ret[5] = fmaf(inp[m], w1[1], ret[5]);
        ret[6] = fmaf(inp[m], w1[2], ret[6]); ret[7] = fmaf(inp[m], w1[3], ret[7]);
      }
      const int sg = s0 + cc;
      const bool valid = (sg <= t) && (sg + WIN > t);
#pragma unroll
      for (int n = 0; n < 8; ++n) {
        float2 k2 = *(const float2*)(&skw2[(n0 + n) * 130 + c * 2]);
        float kd = skdd[(n0 + n) * 66 + c];
        float val = ret[n] + hk0 * k2.x + hk1 * k2.y + inp[n0 + n] * kd;
        float e = valid ? __expf(val) : 0.f;
        zpart[n] += e;
        sS[((n0 + n) * 2 + tj) * SW + cc] = f2bf(e);
      }
    }
    __syncthreads();
  }

  // Z reduction (lanes of a wave share (nh,tj))
#pragma unroll
  for (int n = 0; n < 8; ++n) {
    float z = zpart[n];
    z += __shfl_xor(z, 1);  z += __shfl_xor(z, 2);  z += __shfl_xor(z, 4);
    z += __shfl_xor(z, 8);  z += __shfl_xor(z, 16); z += __shfl_xor(z, 32);
    zpart[n] = 1.0f / z;
  }
  if ((tid & 63) == 0) {
#pragma unroll
    for (int n = 0; n < 8; ++n) srz[tj * 16 + n0 + n] = zpart[n];
  }
  __syncthreads();
  float rz[16];
#pragma unroll
  for (int m = 0; m < 16; ++m) rz[m] = srz[tj * 16 + m];

  // ================= PASS 2 =================
  for (int ch = 0; ch < 5; ++ch) {
    STAGE_KW(kw1_post, kw2_post, kdd_post);
    const int cc = ch * 64 + c;
    float P[16];
    if (cc < SW) {
#pragma unroll
      for (int m = 0; m < 16; ++m) P[m] = bf2f(sS[(m * 2 + tj) * SW + cc]) * rz[m];
    }
    __syncthreads();
    if (cc < SW) {
      float hk0 = 0.f, hk1 = 0.f;
      float ret[8] = {0.f,0.f,0.f,0.f,0.f,0.f,0.f,0.f};
#pragma unroll
      for (int m = 0; m < 16; ++m) {
        float2 k1 = *(const float2*)(&skw1[m * 130 + c * 2]);
        hk0 = fmaf(P[m], k1.x, hk0);
        hk1 = fmaf(P[m], k1.y, hk1);
        const float* MQ = &sMq[(2 + tj) * 256 + m * 16 + n0];
        f32x4 w0 = *(const f32x4*)(MQ);
        f32x4 w1 = *(const f32x4*)(MQ + 4);
        ret[0] = fmaf(P[m], w0[0], ret[0]); ret[1] = fmaf(P[m], w0[1], ret[1]);
        ret[2] = fmaf(P[m], w0[2], ret[2]); ret[3] = fmaf(P[m], w0[3], ret[3]);
        ret[4] = fmaf(P[m], w1[0], ret[4]); ret[5] = fmaf(P[m], w1[1], ret[5]);
        ret[6] = fmaf(P[m], w1[2], ret[6]); ret[7] = fmaf(P[m], w1[3], ret[7]);
      }
#pragma unroll
      for (int n = 0; n < 8; ++n) {
        float2 k2 = *(const float2*)(&skw2[(n0 + n) * 130 + c * 2]);
        float kd = skdd[(n0 + n) * 66 + c];
        float val = ret[n] + hk0 * k2.x + hk1 * k2.y + P[n0 + n] * kd;
        sS[((n0 + n) * 2 + tj) * SW + cc] = f2bf(val);
      }
    }
    __syncthreads();
  }

  // flush P' back over S
#pragma unroll
  for (int it = 0; it < 5; ++it) {
    int idx = tid + it * 256;
    if (idx < 32 * 36) {
      int r = idx / 36, sg = idx % 36;
      int hh = r >> 1, tjj = r & 1;
      uint4 v = *(const uint4*)(&sS[(hh * 2 + tjj) * SW + sg * 8]);
      *(uint4*)(S + ((((long long)(b * NH + hh)) * TT) + t0 + tjj) * SW + sg * 8) = v;
    }
  }
}

// ---------- KC: PV band GEMM per (b,h,32-t tile) ----------
__global__ __launch_bounds__(256, 4)
void kc_pv(const ushort* __restrict__ S, const ushort* __restrict__ v8,
           float* __restrict__ out)
{
  const int tid = threadIdx.x;
  const int raw = blockIdx.x;                  // 1024 = 8*128
  const int job = (raw & 7) * 128 + (raw >> 3);
  const int b = job >> 9, h = (job >> 5) & 15, tt = job & 31;
  const int t0 = tt * 32;
  const int s0 = (t0 >= WIN) ? t0 - WIN : 0;
  const int lane = tid & 63, wv = tid >> 6;

  __shared__ ushort sPt[32 * 296];

  const long long prow0 = (((long long)(b * NH + h)) * TT + t0) * SW;
#pragma unroll
  for (int it = 0; it < 5; ++it) {
    int idx = tid + it * 256;
    if (idx < 32 * 36) {
      int r = idx / 36, sg = idx % 36;
      uint4 v = *(const uint4*)(S + prow0 + (long long)r * SW + sg * 8);
      *(uint4*)(&sPt[r * 296 + sg * 8]) = v;
    }
  }
  __syncthreads();

  const ushort* vbase = v8 + ((long long)(b * NH + h)) * (128 * DD * 8)
                           + ((long long)(s0 >> 3)) * (DD * 8);
  const int dcol = lane & 15, soct = lane >> 4;
  const int dt0 = wv * 2;
  f32x4 acc[2][2];
#pragma unroll
  for (int rt = 0; rt < 2; ++rt)
#pragma unroll
    for (int dd = 0; dd < 2; ++dd) acc[rt][dd] = (f32x4){0.f, 0.f, 0.f, 0.f};

#pragma unroll
  for (int ks = 0; ks < 9; ++ks) {
    s16x8 a0 = *(const s16x8*)(&sPt[(dcol) * 296 + ks * 32 + soct * 8]);
    s16x8 a1 = *(const s16x8*)(&sPt[(16 + dcol) * 296 + ks * 32 + soct * 8]);
#pragma unroll
    for (int dd = 0; dd < 2; ++dd) {
      s16x8 vb = *(const s16x8*)(vbase + (((long long)(ks * 4 + soct)) * DD + (dt0 + dd) * 16 + dcol) * 8);
      acc[0][dd] = __builtin_amdgcn_mfma_f32_16x16x32_bf16(a0, vb, acc[0][dd], 0, 0, 0);
      acc[1][dd] = __builtin_amdgcn_mfma_f32_16x16x32_bf16(a1, vb, acc[1][dd], 0, 0, 0);
    }
  }
  const int r0 = (lane >> 4) * 4;
#pragma unroll
  for (int rt = 0; rt < 2; ++rt)
#pragma unroll
    for (int dd = 0; dd < 2; ++dd)
#pragma unroll
      for (int j = 0; j < 4; ++j) {
        int trow = t0 + rt * 16 + r0 + j;
        out[(((long long)(b * TT + trow)) * NH + h) * DD + (dt0 + dd) * 16 + dcol] = acc[rt][dd][j];
      }
}

extern "C" void kernel_launch(void* const* d_in, const int* in_sizes, int n_in,
                              void* d_out, int out_size, void* d_ws, size_t ws_size,
                              hipStream_t stream) {
  const float* q        = (const float*)d_in[0];
  const float* k        = (const float*)d_in[1];
  const float* v        = (const float*)d_in[2];
  const float* w_pre    = (const float*)d_in[3];
  const float* w_post   = (const float*)d_in[4];
  const float* qw1_pre  = (const float*)d_in[5];
  const float* qw2_pre  = (const float*)d_in[6];
  const float* kw1_pre  = (const float*)d_in[7];
  const float* kw2_pre  = (const float*)d_in[8];
  const float* qw1_post = (const float*)d_in[9];
  const float* qw2_post = (const float*)d_in[10];
  const float* kw1_post = (const float*)d_in[11];
  const float* kw2_post = (const float*)d_in[12];
  const float* qdd_pre  = (const float*)d_in[13];
  const float* kdd_pre  = (const float*)d_in[14];
  const float* qdd_post = (const float*)d_in[15];
  const float* kdd_post = (const float*)d_in[16];
  float* out = (float*)d_out;

  // ws: qb8 8MB | kb8 8MB | v8 8MB | S 18MB  (total 44,040,192 B)
  ushort* qb8 = (ushort*)d_ws;
  ushort* kb8 = (ushort*)((char*)d_ws + 8388608ll);
  ushort* v8  = (ushort*)((char*)d_ws + 16777216ll);
  ushort* S   = (ushort*)((char*)d_ws + 25165824ll);

  prep_qk<<<512, 256, 0, stream>>>(q, qb8, SCALE);
  prep_qk<<<512, 256, 0, stream>>>(k, kb8, 1.0f);
  prep_v <<<512, 256, 0, stream>>>(v, v8);
  ka_qk  <<<1024, 256, 0, stream>>>(qb8, kb8, S);
  kb_proj<<<1024, 256, 0, stream>>>(w_pre, w_post,
                                    qw1_pre, qw2_pre, qdd_pre, kw1_pre, kw2_pre, kdd_pre,
                                    qw1_post, qw2_post, qdd_post, kw1_post, kw2_post, kdd_post,
                                    S);
  kc_pv  <<<1024, 256, 0, stream>>>(S, v8, out);
}